// Round 10
// baseline (3736.633 us; speedup 1.0000x reference)
//
#include <hip/hip_runtime.h>
#include <hip/hip_bf16.h>

typedef unsigned short u16;
typedef unsigned int u32;
using short8 = __attribute__((ext_vector_type(8))) short;
using f32x4  = __attribute__((ext_vector_type(4))) float;

#define DEVINL static __device__ __forceinline__

DEVINL float bf2f(u16 u){
  union { unsigned int i; float f; } x; x.i = ((unsigned int)u) << 16; return x.f;
}
DEVINL u16 f2bf(float f){
  union { float f; unsigned int i; } x; x.f = f;
  unsigned int i = x.i;
  return (u16)((i + 0x7FFFu + ((i >> 16) & 1u)) >> 16);
}
DEVINL u16 f2bf1(float f){
  __hip_bfloat16 b = __float2bfloat16(f);
  u16 u; __builtin_memcpy(&u, &b, 2); return u;
}
DEVINL float fast_sigm(float x){
  float e = __builtin_amdgcn_exp2f(x * -1.442695041f);
  return __builtin_amdgcn_rcpf(1.f + e);
}
DEVINL float fast_tanh(float x){
  x = fminf(fmaxf(x, -10.f), 10.f);
  float e = __builtin_amdgcn_exp2f(x * -2.885390082f);
  return (1.f - e) * __builtin_amdgcn_rcpf(1.f + e);
}
DEVINL f32x4 zero4(){ f32x4 z = {0.f, 0.f, 0.f, 0.f}; return z; }

DEVINL f32x4 mfma16(short8 a, short8 b, f32x4 c){
  return __builtin_amdgcn_mfma_f32_16x16x32_bf16(a, b, c, 0, 0, 0);
}

// lane l: row = l&15, k0 = (l>>4)*8 ; 16B vector read. stride in u16 elements
DEVINL short8 frag_ld(const u16* base, int stride){
  int l = threadIdx.x & 63;
  return *(const short8*)(base + (l & 15) * stride + ((l >> 4) << 3));
}
DEVINL short8 gfrag(const u16* rowbase, int stride, int ks){
  int l = threadIdx.x & 63;
  return *(const short8*)(rowbase + (size_t)(l & 15) * stride + ks * 32 + ((l >> 4) << 3));
}

DEVINL void acc_store_lds(u16* dst, int stride, int col_base, f32x4 acc, float bias, bool relu){
  int l = threadIdx.x & 63;
  int col = col_base + (l & 15);
  int row0 = (l >> 4) * 4;
  #pragma unroll
  for (int r = 0; r < 4; r++){
    float v = acc[r] + bias;
    if (relu) v = fmaxf(v, 0.f);
    dst[(row0 + r) * stride + col] = f2bf(v);
  }
}

DEVINL void stage_weights(u16* dst, const float* src, int N, int K, int Kp){
  int stride = Kp + 8;
  if (Kp > K){
    int padw = Kp - K;
    for (int i = threadIdx.x; i < N * padw; i += blockDim.x){
      int n = i / padw, k = K + (i - (i / padw) * padw);
      dst[n * stride + k] = 0;
    }
  }
  for (int i = threadIdx.x * 4; i < N * K; i += blockDim.x * 4){
    float4 v = *(const float4*)(src + i);
    int n = i / K, k = i - n * K;
    u16* d = dst + n * stride + k;
    d[0] = f2bf(v.x); d[1] = f2bf(v.y); d[2] = f2bf(v.z); d[3] = f2bf(v.w);
  }
}

__global__ __launch_bounds__(256) void k_inith(const float* __restrict__ h0, u16* __restrict__ hst){
  int i = blockIdx.x * 256 + threadIdx.x;
  if (i < 2 * 1024 * 128) hst[i] = f2bf(h0[i]);
}

// ---------------- phase A: phi_u ----------------
__global__ __launch_bounds__(512, 4) void k_phiu(const float* __restrict__ u,
    const float* __restrict__ w0, const float* __restrict__ b0,
    const float* __restrict__ w1, const float* __restrict__ b1,
    u16* __restrict__ phi, int t0, int Tc){
  __shared__ __align__(16) u16 w0s[128 * 40];
  __shared__ __align__(16) u16 w1s[128 * 136];
  __shared__ __align__(16) u16 buf[8][16 * 136];
  stage_weights(w0s, w0, 128, 16, 32);
  stage_weights(w1s, w1, 128, 128, 128);
  int wv = threadIdx.x >> 6, l = threadIdx.x & 63;
  u16* mybuf = buf[wv];
  float b0v[8], b1v[8];
  #pragma unroll
  for (int nt = 0; nt < 8; nt++){
    b0v[nt] = b0[nt * 16 + (l & 15)];
    b1v[nt] = b1[nt * 16 + (l & 15)];
  }
  __syncthreads();
  int tpb = Tc >> 4;
  int ntile = 1024 * tpb;
  int stride = gridDim.x * 8;
  for (int tile = blockIdx.x * 8 + wv; tile < ntile; tile += stride){
    int b = tile / tpb;
    int tt = (tile - b * tpb) << 4;
    int t = l & 15, kb = l >> 4;
    #pragma unroll
    for (int j = 0; j < 4; j++){
      int k = kb + j * 4;
      mybuf[t * 136 + k] = f2bf(u[(size_t)(b * 16 + k) * 1024 + t0 + tt + t]);
      mybuf[t * 136 + 16 + k] = 0;
    }
    short8 a0 = frag_ld(mybuf, 136);
    f32x4 acc[8];
    #pragma unroll
    for (int nt = 0; nt < 8; nt++)
      acc[nt] = mfma16(a0, frag_ld(w0s + nt * 16 * 40, 40), zero4());
    #pragma unroll
    for (int nt = 0; nt < 8; nt++)
      acc_store_lds(mybuf, 136, nt * 16, acc[nt], b0v[nt], true);
    f32x4 a2[8];
    #pragma unroll
    for (int nt = 0; nt < 8; nt++) a2[nt] = zero4();
    #pragma unroll
    for (int ks = 0; ks < 4; ks++){
      short8 a = frag_ld(mybuf + ks * 32, 136);
      #pragma unroll
      for (int nt = 0; nt < 8; nt++)
        a2[nt] = mfma16(a, frag_ld(w1s + nt * 16 * 136 + ks * 32, 136), a2[nt]);
    }
    #pragma unroll
    for (int nt = 0; nt < 8; nt++)
      acc_store_lds(mybuf, 136, nt * 16, a2[nt], b1v[nt], false);
    u16* dst = phi + (size_t)(b * Tc + tt) * 128;
    #pragma unroll
    for (int j = 0; j < 4; j++){
      int c = j * 64 + l;
      int row = c >> 4, k = (c & 15) * 8;
      *(short8*)(dst + row * 128 + k) = *(const short8*)(mybuf + row * 136 + k);
    }
  }
}

// ---------------- phase B: 2-layer GRU, LAYER-SPLIT wave groups ----------------
// 64 blocks x 512 threads. Waves 0-3: layer0 (neurons wv*32..+31, weights wih0/whh0 in regs);
// waves 4-7: layer1 (wih1/whh1). Per step each group runs ONE layer's chain concurrently
// (one L0-wave + one L1-wave per SIMD -> MFMA/VALU/LDS co-schedule). 1 raw barrier/iter.
// phi: coalesced global->reg -> 4-buffer LDS ring (L0 group stages). Hs: L1 group stores.
__global__ __launch_bounds__(512, 1) void k_gru(const u16* __restrict__ phi,
    const float* __restrict__ gwih, const float* __restrict__ gwhh,
    u16* __restrict__ hst, u16* __restrict__ Hs, int Tc){
  __shared__ __align__(16) u16 h0s[2][16 * 136];
  __shared__ __align__(16) u16 h1s[2][16 * 136];
  __shared__ __align__(16) u16 pb[4][16 * 136];
  const int l = threadIdx.x & 63;
  const bool isL0 = (threadIdx.x < 256);
  const int wv4 = (threadIdx.x >> 6) & 3;
  const int b0 = blockIdx.x * 16;
  const int m0 = (l >> 4) * 4;
  const int cc = l & 15;
  const int nb = wv4 * 32;   // 32 neurons per wave (2 n-tiles)

  // register weights for THIS wave's layer: Wr[0]=input-side, Wr[1]=hidden-side
  const float* wsrc[2] = { isL0 ? gwih : gwih + 49152, isL0 ? gwhh : gwhh + 49152 };
  short8 Wr[2][3][2][4];
  #pragma unroll
  for (int mm = 0; mm < 2; mm++){
    #pragma unroll
    for (int g = 0; g < 3; g++){
      #pragma unroll
      for (int nt = 0; nt < 2; nt++){
        int n = g * 128 + nb + nt * 16 + cc;
        #pragma unroll
        for (int ks = 0; ks < 4; ks++){
          const float* p = wsrc[mm] + (size_t)n * 128 + ks * 32 + ((l >> 4) << 3);
          float4 va = *(const float4*)p;
          float4 vb = *(const float4*)(p + 4);
          short8 f;
          f[0] = (short)f2bf(va.x); f[1] = (short)f2bf(va.y);
          f[2] = (short)f2bf(va.z); f[3] = (short)f2bf(va.w);
          f[4] = (short)f2bf(vb.x); f[5] = (short)f2bf(vb.y);
          f[6] = (short)f2bf(vb.z); f[7] = (short)f2bf(vb.w);
          Wr[mm][g][nt][ks] = f;
        }
      }
    }
  }
  // restore state (512 threads: 8B each per tile)
  {
    int row = threadIdx.x >> 5, k0 = (threadIdx.x & 31) * 4;
    *(uint2*)(&h0s[0][row * 136 + k0]) = *(const uint2*)(hst + (size_t)(b0 + row) * 128 + k0);
    *(uint2*)(&h1s[0][row * 136 + k0]) = *(const uint2*)(hst + 131072 + (size_t)(b0 + row) * 128 + k0);
  }
  // owned h elements (L0 waves: h0; L1 waves: h1)
  const u16* hbase = hst + (isL0 ? 0 : 131072);
  float hp[2][4];
  #pragma unroll
  for (int nt = 0; nt < 2; nt++)
    #pragma unroll
    for (int r = 0; r < 4; r++)
      hp[nt][r] = bf2f(hbase[(size_t)(b0 + m0 + r) * 128 + nb + nt * 16 + cc]);

  // group-local staging maps (16B grain, 256 threads per group)
  const int gp = threadIdx.x & 255;
  const int srow = gp >> 4, sk = (gp & 15) * 8;
  const u16* pL0 = phi + (size_t)(b0 + srow) * Tc * 128 + sk;   // L0: phi source
  u16* Hp = Hs + (size_t)(b0 + srow) * Tc * 128 + sk;           // L1: Hs dest
  uint4 pfA, pfB;
  if (isL0){
    *(uint4*)(&pb[0][srow * 136 + sk]) = *(const uint4*)(pL0);
    *(uint4*)(&pb[1][srow * 136 + sk]) = *(const uint4*)(pL0 + 128);
    pfA = *(const uint4*)(pL0 + 2 * 128);
    pfB = *(const uint4*)(pL0 + 3 * 128);
  }
  __syncthreads();

  // ITER(i): L1 group finishes GRU step i-1 (reads h0s[P]=H0[i], h1s[P^1]=H1[i-2] state,
  //          writes h1s[P]=H1[i-1], stores Hs(i-1)); L0 group computes H0[i+1] from
  //          (h0s[P], phi(i) in pb[q]) -> h0s[P^1]. Same indexing as r9 (verified).
  auto ITER = [&](int i, int P, int q, uint4& pf){
    if (isL0){
      if (i < Tc){
        short8 a0[4], ap[4];
        #pragma unroll
        for (int ks = 0; ks < 4; ks++){
          a0[ks] = frag_ld(h0s[P] + ks * 32, 136);
          ap[ks] = frag_ld(pb[q] + ks * 32, 136);
        }
        f32x4 cr[2], cz[2], cin[2], chn[2];
        #pragma unroll
        for (int nt = 0; nt < 2; nt++){ cr[nt]=zero4(); cz[nt]=zero4(); cin[nt]=zero4(); chn[nt]=zero4(); }
        __builtin_amdgcn_s_setprio(1);
        #pragma unroll
        for (int ks = 0; ks < 4; ks++)
          #pragma unroll
          for (int nt = 0; nt < 2; nt++){
            cr[nt]  = mfma16(ap[ks], Wr[0][0][nt][ks], cr[nt]);
            cr[nt]  = mfma16(a0[ks], Wr[1][0][nt][ks], cr[nt]);
            cz[nt]  = mfma16(ap[ks], Wr[0][1][nt][ks], cz[nt]);
            cz[nt]  = mfma16(a0[ks], Wr[1][1][nt][ks], cz[nt]);
            cin[nt] = mfma16(ap[ks], Wr[0][2][nt][ks], cin[nt]);
            chn[nt] = mfma16(a0[ks], Wr[1][2][nt][ks], chn[nt]);
          }
        __builtin_amdgcn_s_setprio(0);
        if (i + 2 < Tc) *(uint4*)(&pb[(q + 2) & 3][srow * 136 + sk]) = pf;
        if (i + 4 < Tc) pf = *(const uint4*)(pL0 + (size_t)(i + 4) * 128);
        #pragma unroll
        for (int nt = 0; nt < 2; nt++)
          #pragma unroll
          for (int r = 0; r < 4; r++){
            float rg = fast_sigm(cr[nt][r]);
            float zg = fast_sigm(cz[nt][r]);
            float ng = fast_tanh(cin[nt][r] + rg * chn[nt][r]);
            float hv = zg * (hp[nt][r] - ng) + ng;
            hp[nt][r] = hv;
            h0s[P ^ 1][(m0 + r) * 136 + nb + nt * 16 + cc] = f2bf1(hv);
          }
      }
    } else {
      if (i > 0){
        short8 a0[4], a1[4];
        #pragma unroll
        for (int ks = 0; ks < 4; ks++){
          a0[ks] = frag_ld(h0s[P] + ks * 32, 136);
          a1[ks] = frag_ld(h1s[P ^ 1] + ks * 32, 136);
        }
        *(uint4*)(Hp + (size_t)(i - 1) * 128) = *(const uint4*)(&h1s[P ^ 1][srow * 136 + sk]);
        f32x4 cr[2], cz[2], cin[2], chn[2];
        #pragma unroll
        for (int nt = 0; nt < 2; nt++){ cr[nt]=zero4(); cz[nt]=zero4(); cin[nt]=zero4(); chn[nt]=zero4(); }
        __builtin_amdgcn_s_setprio(1);
        #pragma unroll
        for (int ks = 0; ks < 4; ks++)
          #pragma unroll
          for (int nt = 0; nt < 2; nt++){
            cr[nt]  = mfma16(a0[ks], Wr[0][0][nt][ks], cr[nt]);
            cr[nt]  = mfma16(a1[ks], Wr[1][0][nt][ks], cr[nt]);
            cz[nt]  = mfma16(a0[ks], Wr[0][1][nt][ks], cz[nt]);
            cz[nt]  = mfma16(a1[ks], Wr[1][1][nt][ks], cz[nt]);
            cin[nt] = mfma16(a0[ks], Wr[0][2][nt][ks], cin[nt]);
            chn[nt] = mfma16(a1[ks], Wr[1][2][nt][ks], chn[nt]);
          }
        __builtin_amdgcn_s_setprio(0);
        #pragma unroll
        for (int nt = 0; nt < 2; nt++)
          #pragma unroll
          for (int r = 0; r < 4; r++){
            float rg = fast_sigm(cr[nt][r]);
            float zg = fast_sigm(cz[nt][r]);
            float ng = fast_tanh(cin[nt][r] + rg * chn[nt][r]);
            float hv = zg * (hp[nt][r] - ng) + ng;
            hp[nt][r] = hv;
            h1s[P][(m0 + r) * 136 + nb + nt * 16 + cc] = f2bf1(hv);
          }
      }
    }
    asm volatile("s_waitcnt lgkmcnt(0)" ::: "memory");
    __builtin_amdgcn_s_barrier();
    asm volatile("" ::: "memory");
  };

  for (int i = 0; i < Tc; i += 4){
    ITER(i + 0, 0, 0, pfA);
    ITER(i + 1, 1, 1, pfB);
    ITER(i + 2, 0, 2, pfA);
    ITER(i + 3, 1, 3, pfB);
  }
  ITER(Tc, 0, 0, pfA);   // epilogue: layer1 of step Tc-1 + Hs slot Tc-1
  // save state (Tc even: finals in h0s[0], h1s[0])
  {
    int row = threadIdx.x >> 5, k0 = (threadIdx.x & 31) * 4;
    *(uint2*)(hst + (size_t)(b0 + row) * 128 + k0) = *(const uint2*)(&h0s[0][row * 136 + k0]);
    *(uint2*)(hst + 131072 + (size_t)(b0 + row) * 128 + k0) = *(const uint2*)(&h1s[0][row * 136 + k0]);
  }
}

// ---------------- phase C1: dynn + x_mean/x_logvar ----------------
__global__ __launch_bounds__(512, 2) void k_c1(const u16* __restrict__ phi, const u16* __restrict__ Hs,
    const float* __restrict__ dw0, const float* __restrict__ db0,
    const float* __restrict__ dw1, const float* __restrict__ db1,
    const float* __restrict__ xmw, const float* __restrict__ xmb,
    const float* __restrict__ xlw, const float* __restrict__ xlb,
    u16* __restrict__ xmlv, int Tc){
  __shared__ __align__(16) u16 w0s[128 * 264];
  __shared__ __align__(16) u16 w1s[128 * 136];
  __shared__ __align__(16) u16 xws[32 * 136];
  __shared__ __align__(16) u16 buf[8][16 * 136];
  stage_weights(w0s, dw0, 128, 256, 256);
  stage_weights(w1s, dw1, 128, 128, 128);
  stage_weights(xws, xmw, 16, 128, 128);
  stage_weights(xws + 16 * 136, xlw, 16, 128, 128);
  int wv = threadIdx.x >> 6, l = threadIdx.x & 63;
  u16* mybuf = buf[wv];
  float b0v[8], b1v[8];
  #pragma unroll
  for (int nt = 0; nt < 8; nt++){
    b0v[nt] = db0[nt * 16 + (l & 15)];
    b1v[nt] = db1[nt * 16 + (l & 15)];
  }
  float bxm = xmb[l & 15], bxl = xlb[l & 15];
  __syncthreads();
  int tpb = Tc >> 4;
  int ntile = 1024 * tpb;
  int stride = gridDim.x * 8;
  for (int tile = blockIdx.x * 8 + wv; tile < ntile; tile += stride){
    int b = tile / tpb;
    int tt = (tile - b * tpb) << 4;
    size_t rbase = (size_t)(b * Tc + tt);
    const u16* ap = phi + rbase * 128;
    const u16* hp = Hs + rbase * 128;
    f32x4 acc[8];
    #pragma unroll
    for (int nt = 0; nt < 8; nt++) acc[nt] = zero4();
    #pragma unroll
    for (int ks = 0; ks < 8; ks++){
      short8 a = (ks < 4) ? gfrag(ap, 128, ks) : gfrag(hp, 128, ks - 4);
      #pragma unroll
      for (int nt = 0; nt < 8; nt++)
        acc[nt] = mfma16(a, frag_ld(w0s + nt * 16 * 264 + ks * 32, 264), acc[nt]);
    }
    #pragma unroll
    for (int nt = 0; nt < 8; nt++)
      acc_store_lds(mybuf, 136, nt * 16, acc[nt], b0v[nt], true);
    f32x4 a2[8];
    #pragma unroll
    for (int nt = 0; nt < 8; nt++) a2[nt] = zero4();
    #pragma unroll
    for (int ks = 0; ks < 4; ks++){
      short8 a = frag_ld(mybuf + ks * 32, 136);
      #pragma unroll
      for (int nt = 0; nt < 8; nt++)
        a2[nt] = mfma16(a, frag_ld(w1s + nt * 16 * 136 + ks * 32, 136), a2[nt]);
    }
    #pragma unroll
    for (int nt = 0; nt < 8; nt++)
      acc_store_lds(mybuf, 136, nt * 16, a2[nt], b1v[nt], false);
    f32x4 am = zero4(), al = zero4();
    #pragma unroll
    for (int ks = 0; ks < 4; ks++){
      short8 a = frag_ld(mybuf + ks * 32, 136);
      am = mfma16(a, frag_ld(xws + ks * 32, 136), am);
      al = mfma16(a, frag_ld(xws + 16 * 136 + ks * 32, 136), al);
    }
    acc_store_lds(mybuf, 136, 0, am, bxm, false);
    acc_store_lds(mybuf, 136, 16, al, bxl, false);
    u16* dst = xmlv + rbase * 32;
    int c = l;
    int row = c >> 2, k = (c & 3) * 8;
    *(short8*)(dst + row * 32 + k) = *(const short8*)(mybuf + row * 136 + k);
  }
}

// ---------------- phase C2: phi_x + menn + C@x_mean + loss ----------------
__global__ __launch_bounds__(512, 2) void k_c2(const u16* __restrict__ xmlv, const float* __restrict__ y,
    const float* __restrict__ pw0, const float* __restrict__ pb0,
    const float* __restrict__ pw1, const float* __restrict__ pb1,
    const float* __restrict__ mw0, const float* __restrict__ mb0,
    const float* __restrict__ mw1, const float* __restrict__ mb1,
    const float* __restrict__ Cw, float* __restrict__ out, int t0, int Tc){
  __shared__ __align__(16) u16 pw0s[128 * 40];
  __shared__ __align__(16) u16 pw1s[128 * 136];
  __shared__ __align__(16) u16 mw0s[128 * 136];
  __shared__ __align__(16) u16 mw1s[16 * 136];
  __shared__ __align__(16) u16 Cs[16 * 40];
  __shared__ __align__(16) u16 buf[8][16 * 136];
  stage_weights(pw0s, pw0, 128, 32, 32);
  stage_weights(pw1s, pw1, 128, 128, 128);
  stage_weights(mw0s, mw0, 128, 128, 128);
  stage_weights(mw1s, mw1, 16, 128, 128);
  stage_weights(Cs, Cw, 16, 16, 32);
  int wv = threadIdx.x >> 6, l = threadIdx.x & 63;
  u16* mybuf = buf[wv];
  float bp0v[8], bp1v[8], bm0v[8];
  #pragma unroll
  for (int nt = 0; nt < 8; nt++){
    bp0v[nt] = pb0[nt * 16 + (l & 15)];
    bp1v[nt] = pb1[nt * 16 + (l & 15)];
    bm0v[nt] = mb0[nt * 16 + (l & 15)];
  }
  float bm1 = mb1[l & 15];
  __syncthreads();
  float lacc = 0.f;
  int tpb = Tc >> 4;
  int ntile = 1024 * tpb;
  int stride = gridDim.x * 8;
  for (int tile = blockIdx.x * 8 + wv; tile < ntile; tile += stride){
    int b = tile / tpb;
    int tt = (tile - b * tpb) << 4;
    size_t rbase = (size_t)(b * Tc + tt);
    const u16* xp = xmlv + rbase * 32;
    short8 a0 = gfrag(xp, 32, 0);
    f32x4 acc[8];
    #pragma unroll
    for (int nt = 0; nt < 8; nt++)
      acc[nt] = mfma16(a0, frag_ld(pw0s + nt * 16 * 40, 40), zero4());
    #pragma unroll
    for (int nt = 0; nt < 8; nt++)
      acc_store_lds(mybuf, 136, nt * 16, acc[nt], bp0v[nt], true);
    f32x4 a2[8];
    #pragma unroll
    for (int nt = 0; nt < 8; nt++) a2[nt] = zero4();
    #pragma unroll
    for (int ks = 0; ks < 4; ks++){
      short8 a = frag_ld(mybuf + ks * 32, 136);
      #pragma unroll
      for (int nt = 0; nt < 8; nt++)
        a2[nt] = mfma16(a, frag_ld(pw1s + nt * 16 * 136 + ks * 32, 136), a2[nt]);
    }
    #pragma unroll
    for (int nt = 0; nt < 8; nt++)
      acc_store_lds(mybuf, 136, nt * 16, a2[nt], bp1v[nt], false);
    f32x4 a3[8];
    #pragma unroll
    for (int nt = 0; nt < 8; nt++) a3[nt] = zero4();
    #pragma unroll
    for (int ks = 0; ks < 4; ks++){
      short8 a = frag_ld(mybuf + ks * 32, 136);
      #pragma unroll
      for (int nt = 0; nt < 8; nt++)
        a3[nt] = mfma16(a, frag_ld(mw0s + nt * 16 * 136 + ks * 32, 136), a3[nt]);
    }
    #pragma unroll
    for (int nt = 0; nt < 8; nt++)
      acc_store_lds(mybuf, 136, nt * 16, a3[nt], bm0v[nt], true);
    f32x4 ay = zero4();
    #pragma unroll
    for (int ks = 0; ks < 4; ks++){
      short8 a = frag_ld(mybuf + ks * 32, 136);
      ay = mfma16(a, frag_ld(mw1s + ks * 32, 136), ay);
    }
    f32x4 ac = mfma16(a0, frag_ld(Cs, 40), zero4());
    #pragma unroll
    for (int r = 0; r < 4; r++){
      float yh = ay[r] + bm1 + ac[r];
      int m = (l >> 4) * 4 + r, j = l & 15;
      float d = yh - y[(size_t)(b * 16 + j) * 1024 + t0 + tt + m];
      lacc += d * d;
    }
  }
  #pragma unroll
  for (int off = 32; off > 0; off >>= 1)
    lacc += __shfl_down(lacc, off);
  if (l == 0) atomicAdd(out, lacc);
}

extern "C" void kernel_launch(void* const* d_in, const int* in_sizes, int n_in,
                              void* d_out, int out_size, void* d_ws, size_t ws_size,
                              hipStream_t stream){
  const float* u    = (const float*)d_in[0];
  const float* y    = (const float*)d_in[1];
  const float* h0   = (const float*)d_in[2];
  const float* puw0 = (const float*)d_in[3];
  const float* pub0 = (const float*)d_in[4];
  const float* puw1 = (const float*)d_in[5];
  const float* pub1 = (const float*)d_in[6];
  const float* dw0  = (const float*)d_in[7];
  const float* db0  = (const float*)d_in[8];
  const float* dw1  = (const float*)d_in[9];
  const float* db1  = (const float*)d_in[10];
  const float* xmw  = (const float*)d_in[11];
  const float* xmb  = (const float*)d_in[12];
  const float* xlw  = (const float*)d_in[13];
  const float* xlb  = (const float*)d_in[14];
  const float* pxw0 = (const float*)d_in[15];
  const float* pxb0 = (const float*)d_in[16];
  const float* pxw1 = (const float*)d_in[17];
  const float* pxb1 = (const float*)d_in[18];
  const float* mw0  = (const float*)d_in[19];
  const float* mb0  = (const float*)d_in[20];
  const float* mw1  = (const float*)d_in[21];
  const float* mb1  = (const float*)d_in[22];
  const float* gwih = (const float*)d_in[23];
  const float* gwhh = (const float*)d_in[24];
  const float* Cw   = (const float*)d_in[25];

  char* w = (char*)d_ws;
  u16* hst = (u16*)w; w += (size_t)2 * 1024 * 128 * 2;
  size_t head = (size_t)2 * 1024 * 128 * 2 + 4096;
  size_t avail = (ws_size > head) ? (ws_size - head) : 0;
  int Tc = 1024;
  while (Tc > 64 && (size_t)1024 * (size_t)Tc * (128 + 128 + 32) * 2 > avail) Tc >>= 1;
  u16* phi  = (u16*)w; w += (size_t)1024 * Tc * 128 * 2;
  u16* Hs   = (u16*)w; w += (size_t)1024 * Tc * 128 * 2;
  u16* xmlv = (u16*)w; w += (size_t)1024 * Tc * 32 * 2;

  hipMemsetAsync(d_out, 0, sizeof(float), stream);
  k_inith<<<1024, 256, 0, stream>>>(h0, hst);
  for (int t0 = 0; t0 < 1024; t0 += Tc){
    k_phiu<<<512, 512, 0, stream>>>(u, puw0, pub0, puw1, pub1, phi, t0, Tc);
    k_gru<<<64, 512, 0, stream>>>(phi, gwih, gwhh, hst, Hs, Tc);
    k_c1<<<256, 512, 0, stream>>>(phi, Hs, dw0, db0, dw1, db1, xmw, xmb, xlw, xlb, xmlv, Tc);
    k_c2<<<256, 512, 0, stream>>>(xmlv, y, pxw0, pxb0, pxw1, pxb1, mw0, mb0, mw1, mb1, Cw,
                                  (float*)d_out, t0, Tc);
  }
}

// Round 11
// 3407.105 us; speedup vs baseline: 1.0967x; 1.0967x over previous
//
#include <hip/hip_runtime.h>
#include <hip/hip_bf16.h>

typedef unsigned short u16;
typedef unsigned int u32;
using short8 = __attribute__((ext_vector_type(8))) short;
using f32x4  = __attribute__((ext_vector_type(4))) float;

#define DEVINL static __device__ __forceinline__

DEVINL float bf2f(u16 u){
  union { unsigned int i; float f; } x; x.i = ((unsigned int)u) << 16; return x.f;
}
DEVINL u16 f2bf(float f){
  union { float f; unsigned int i; } x; x.f = f;
  unsigned int i = x.i;
  return (u16)((i + 0x7FFFu + ((i >> 16) & 1u)) >> 16);
}
DEVINL u16 f2bf1(float f){
  __hip_bfloat16 b = __float2bfloat16(f);
  u16 u; __builtin_memcpy(&u, &b, 2); return u;
}
DEVINL float fast_sigm(float x){
  float e = __builtin_amdgcn_exp2f(x * -1.442695041f);
  return __builtin_amdgcn_rcpf(1.f + e);
}
DEVINL float fast_tanh(float x){
  x = fminf(fmaxf(x, -10.f), 10.f);
  float e = __builtin_amdgcn_exp2f(x * -2.885390082f);
  return (1.f - e) * __builtin_amdgcn_rcpf(1.f + e);
}
DEVINL f32x4 zero4(){ f32x4 z = {0.f, 0.f, 0.f, 0.f}; return z; }

DEVINL f32x4 mfma16(short8 a, short8 b, f32x4 c){
  return __builtin_amdgcn_mfma_f32_16x16x32_bf16(a, b, c, 0, 0, 0);
}

// lane l: row = l&15, k0 = (l>>4)*8 ; 16B vector read. stride in u16 elements
DEVINL short8 frag_ld(const u16* base, int stride){
  int l = threadIdx.x & 63;
  return *(const short8*)(base + (l & 15) * stride + ((l >> 4) << 3));
}
DEVINL short8 gfrag(const u16* rowbase, int stride, int ks){
  int l = threadIdx.x & 63;
  return *(const short8*)(rowbase + (size_t)(l & 15) * stride + ks * 32 + ((l >> 4) << 3));
}

DEVINL void acc_store_lds(u16* dst, int stride, int col_base, f32x4 acc, float bias, bool relu){
  int l = threadIdx.x & 63;
  int col = col_base + (l & 15);
  int row0 = (l >> 4) * 4;
  #pragma unroll
  for (int r = 0; r < 4; r++){
    float v = acc[r] + bias;
    if (relu) v = fmaxf(v, 0.f);
    dst[(row0 + r) * stride + col] = f2bf(v);
  }
}

DEVINL void stage_weights(u16* dst, const float* src, int N, int K, int Kp){
  int stride = Kp + 8;
  if (Kp > K){
    int padw = Kp - K;
    for (int i = threadIdx.x; i < N * padw; i += blockDim.x){
      int n = i / padw, k = K + (i - (i / padw) * padw);
      dst[n * stride + k] = 0;
    }
  }
  for (int i = threadIdx.x * 4; i < N * K; i += blockDim.x * 4){
    float4 v = *(const float4*)(src + i);
    int n = i / K, k = i - n * K;
    u16* d = dst + n * stride + k;
    d[0] = f2bf(v.x); d[1] = f2bf(v.y); d[2] = f2bf(v.z); d[3] = f2bf(v.w);
  }
}

__global__ __launch_bounds__(256) void k_inith(const float* __restrict__ h0, u16* __restrict__ hst){
  int i = blockIdx.x * 256 + threadIdx.x;
  if (i < 2 * 1024 * 128) hst[i] = f2bf(h0[i]);
}

// ---------------- phase A: phi_u ----------------
__global__ __launch_bounds__(512, 4) void k_phiu(const float* __restrict__ u,
    const float* __restrict__ w0, const float* __restrict__ b0,
    const float* __restrict__ w1, const float* __restrict__ b1,
    u16* __restrict__ phi, int t0, int Tc){
  __shared__ __align__(16) u16 w0s[128 * 40];
  __shared__ __align__(16) u16 w1s[128 * 136];
  __shared__ __align__(16) u16 buf[8][16 * 136];
  stage_weights(w0s, w0, 128, 16, 32);
  stage_weights(w1s, w1, 128, 128, 128);
  int wv = threadIdx.x >> 6, l = threadIdx.x & 63;
  u16* mybuf = buf[wv];
  float b0v[8], b1v[8];
  #pragma unroll
  for (int nt = 0; nt < 8; nt++){
    b0v[nt] = b0[nt * 16 + (l & 15)];
    b1v[nt] = b1[nt * 16 + (l & 15)];
  }
  __syncthreads();
  int tpb = Tc >> 4;
  int ntile = 1024 * tpb;
  int stride = gridDim.x * 8;
  for (int tile = blockIdx.x * 8 + wv; tile < ntile; tile += stride){
    int b = tile / tpb;
    int tt = (tile - b * tpb) << 4;
    int t = l & 15, kb = l >> 4;
    #pragma unroll
    for (int j = 0; j < 4; j++){
      int k = kb + j * 4;
      mybuf[t * 136 + k] = f2bf(u[(size_t)(b * 16 + k) * 1024 + t0 + tt + t]);
      mybuf[t * 136 + 16 + k] = 0;
    }
    short8 a0 = frag_ld(mybuf, 136);
    f32x4 acc[8];
    #pragma unroll
    for (int nt = 0; nt < 8; nt++)
      acc[nt] = mfma16(a0, frag_ld(w0s + nt * 16 * 40, 40), zero4());
    #pragma unroll
    for (int nt = 0; nt < 8; nt++)
      acc_store_lds(mybuf, 136, nt * 16, acc[nt], b0v[nt], true);
    f32x4 a2[8];
    #pragma unroll
    for (int nt = 0; nt < 8; nt++) a2[nt] = zero4();
    #pragma unroll
    for (int ks = 0; ks < 4; ks++){
      short8 a = frag_ld(mybuf + ks * 32, 136);
      #pragma unroll
      for (int nt = 0; nt < 8; nt++)
        a2[nt] = mfma16(a, frag_ld(w1s + nt * 16 * 136 + ks * 32, 136), a2[nt]);
    }
    #pragma unroll
    for (int nt = 0; nt < 8; nt++)
      acc_store_lds(mybuf, 136, nt * 16, a2[nt], b1v[nt], false);
    u16* dst = phi + (size_t)(b * Tc + tt) * 128;
    #pragma unroll
    for (int j = 0; j < 4; j++){
      int c = j * 64 + l;
      int row = c >> 4, k = (c & 15) * 8;
      *(short8*)(dst + row * 128 + k) = *(const short8*)(mybuf + row * 136 + k);
    }
  }
}

// ---------------- phase B: 2-layer GRU, 4 waves x 16 rows x 32 neurons/wave ----------------
// r9 structure verbatim EXCEPT the loop sync: clobber-less lgkmcnt + raw s_barrier +
// sched_barrier(0) pinning (no "memory" clobber -> no per-iter vmcnt(0) drain; Hs stores
// and phi prefetch loads stay in flight across barriers).
__global__ __launch_bounds__(256, 1) void k_gru(const u16* __restrict__ phi,
    const float* __restrict__ gwih, const float* __restrict__ gwhh,
    u16* __restrict__ hst, u16* __restrict__ Hs, int Tc){
  __shared__ __align__(16) u16 wi0[384 * 136];     // 104448 B
  __shared__ __align__(16) u16 h0s[2][16 * 136];
  __shared__ __align__(16) u16 h1s[2][16 * 136];
  __shared__ __align__(16) u16 pb[4][16 * 136];
  const int l = threadIdx.x & 63;
  const int wv = threadIdx.x >> 6;          // 0..3
  const int b0 = blockIdx.x * 16;
  const int m0 = (l >> 4) * 4;
  const int cc = l & 15;
  const int nb = wv * 32;                   // neuron base of this wave (2 tiles: nb, nb+16)

  stage_weights(wi0, gwih, 384, 128, 128);  // layer0 W_ih in LDS

  // register weights: Wr[0]=whh0, Wr[1]=wih1, Wr[2]=whh1 ; [mat][gate][ntile][ks]
  const float* srcs[3] = { gwhh, gwih + 49152, gwhh + 49152 };
  short8 Wr[3][3][2][4];
  #pragma unroll
  for (int mm = 0; mm < 3; mm++){
    #pragma unroll
    for (int g = 0; g < 3; g++){
      #pragma unroll
      for (int nt = 0; nt < 2; nt++){
        int n = g * 128 + nb + nt * 16 + cc;
        #pragma unroll
        for (int ks = 0; ks < 4; ks++){
          const float* p = srcs[mm] + (size_t)n * 128 + ks * 32 + ((l >> 4) << 3);
          float4 va = *(const float4*)p;
          float4 vb = *(const float4*)(p + 4);
          short8 f;
          f[0] = (short)f2bf(va.x); f[1] = (short)f2bf(va.y);
          f[2] = (short)f2bf(va.z); f[3] = (short)f2bf(va.w);
          f[4] = (short)f2bf(vb.x); f[5] = (short)f2bf(vb.y);
          f[6] = (short)f2bf(vb.z); f[7] = (short)f2bf(vb.w);
          Wr[mm][g][nt][ks] = f;
        }
      }
    }
  }
  // per-thread copy map: 256 threads x 16B covers one 16x128 tile
  const int row = threadIdx.x >> 4, k0 = (threadIdx.x & 15) * 8;
  // restore state
  *(uint4*)(&h0s[0][row * 136 + k0]) = *(const uint4*)(hst + (size_t)(b0 + row) * 128 + k0);
  *(uint4*)(&h1s[0][row * 136 + k0]) = *(const uint4*)(hst + 131072 + (size_t)(b0 + row) * 128 + k0);
  float hp0[2][4], hp1[2][4];
  #pragma unroll
  for (int nt = 0; nt < 2; nt++)
    #pragma unroll
    for (int r = 0; r < 4; r++){
      hp0[nt][r] = bf2f(hst[(size_t)(b0 + m0 + r) * 128 + nb + nt * 16 + cc]);
      hp1[nt][r] = bf2f(hst[131072 + (size_t)(b0 + m0 + r) * 128 + nb + nt * 16 + cc]);
    }
  // phi source / Hs dest pointers (coalesced, 16B grain)
  const u16* pL = phi + (size_t)(b0 + row) * Tc * 128 + k0;
  u16* Hp = Hs + (size_t)(b0 + row) * Tc * 128 + k0;
  // prologue: pb[0]=phi(0), pb[1]=phi(1); regs pfA=phi(2), pfB=phi(3)
  *(uint4*)(&pb[0][row * 136 + k0]) = *(const uint4*)(pL);
  *(uint4*)(&pb[1][row * 136 + k0]) = *(const uint4*)(pL + 128);
  uint4 pfA = *(const uint4*)(pL + 2 * 128);
  uint4 pfB = *(const uint4*)(pL + 3 * 128);
  __syncthreads();

  // ITER(i): layer1 finishes GRU step i-1 (reads h0s[P]=H0[i], h1s[P^1]=H1[i-1] -> h1s[P]);
  //          layer0 computes H0[i+1] from (h0s[P], phi(i) in pb[q]) -> h0s[P^1].
  auto ITER = [&](int i, int P, int q, uint4& pf){
    short8 a0[4];
    #pragma unroll
    for (int ks = 0; ks < 4; ks++) a0[ks] = frag_ld(h0s[P] + ks * 32, 136);
    if (i > 0){
      short8 a1[4];
      #pragma unroll
      for (int ks = 0; ks < 4; ks++) a1[ks] = frag_ld(h1s[P ^ 1] + ks * 32, 136);
      *(uint4*)(Hp + (size_t)(i - 1) * 128) = *(const uint4*)(&h1s[P ^ 1][row * 136 + k0]);
      f32x4 cr[2], cz[2], cin[2], chn[2];
      #pragma unroll
      for (int nt = 0; nt < 2; nt++){ cr[nt]=zero4(); cz[nt]=zero4(); cin[nt]=zero4(); chn[nt]=zero4(); }
      #pragma unroll
      for (int ks = 0; ks < 4; ks++)
        #pragma unroll
        for (int nt = 0; nt < 2; nt++){
          cr[nt]  = mfma16(a0[ks], Wr[1][0][nt][ks], cr[nt]);   // wih1
          cr[nt]  = mfma16(a1[ks], Wr[2][0][nt][ks], cr[nt]);   // whh1
          cz[nt]  = mfma16(a0[ks], Wr[1][1][nt][ks], cz[nt]);
          cz[nt]  = mfma16(a1[ks], Wr[2][1][nt][ks], cz[nt]);
          cin[nt] = mfma16(a0[ks], Wr[1][2][nt][ks], cin[nt]);
          chn[nt] = mfma16(a1[ks], Wr[2][2][nt][ks], chn[nt]);
        }
      #pragma unroll
      for (int nt = 0; nt < 2; nt++)
        #pragma unroll
        for (int r = 0; r < 4; r++){
          float rg = fast_sigm(cr[nt][r]);
          float zg = fast_sigm(cz[nt][r]);
          float ng = fast_tanh(cin[nt][r] + rg * chn[nt][r]);
          float hv = zg * (hp1[nt][r] - ng) + ng;
          hp1[nt][r] = hv;
          h1s[P][(m0 + r) * 136 + nb + nt * 16 + cc] = f2bf1(hv);
        }
    }
    if (i < Tc){
      short8 ap[4];
      #pragma unroll
      for (int ks = 0; ks < 4; ks++) ap[ks] = frag_ld(pb[q] + ks * 32, 136);
      f32x4 cr[2], cz[2], cin[2], chn[2];
      #pragma unroll
      for (int nt = 0; nt < 2; nt++){ cr[nt]=zero4(); cz[nt]=zero4(); cin[nt]=zero4(); chn[nt]=zero4(); }
      #pragma unroll
      for (int ks = 0; ks < 4; ks++)
        #pragma unroll
        for (int nt = 0; nt < 2; nt++){
          cr[nt]  = mfma16(ap[ks], frag_ld(wi0 + (0 * 128 + nb + nt * 16) * 136 + ks * 32, 136), cr[nt]);
          cr[nt]  = mfma16(a0[ks], Wr[0][0][nt][ks], cr[nt]);   // whh0
          cz[nt]  = mfma16(ap[ks], frag_ld(wi0 + (1 * 128 + nb + nt * 16) * 136 + ks * 32, 136), cz[nt]);
          cz[nt]  = mfma16(a0[ks], Wr[0][1][nt][ks], cz[nt]);
          cin[nt] = mfma16(ap[ks], frag_ld(wi0 + (2 * 128 + nb + nt * 16) * 136 + ks * 32, 136), cin[nt]);
          chn[nt] = mfma16(a0[ks], Wr[0][2][nt][ks], chn[nt]);
        }
      // late: stage phi(i+2) into ring; issue load of phi(i+4)
      if (i + 2 < Tc) *(uint4*)(&pb[(q + 2) & 3][row * 136 + k0]) = pf;
      if (i + 4 < Tc) pf = *(const uint4*)(pL + (size_t)(i + 4) * 128);
      #pragma unroll
      for (int nt = 0; nt < 2; nt++)
        #pragma unroll
        for (int r = 0; r < 4; r++){
          float rg = fast_sigm(cr[nt][r]);
          float zg = fast_sigm(cz[nt][r]);
          float ng = fast_tanh(cin[nt][r] + rg * chn[nt][r]);
          float hv = zg * (hp0[nt][r] - ng) + ng;
          hp0[nt][r] = hv;
          h0s[P ^ 1][(m0 + r) * 136 + nb + nt * 16 + cc] = f2bf1(hv);
        }
    }
    // clobber-less sync: drain LDS only; global stores/loads remain in flight.
    __builtin_amdgcn_sched_barrier(0);
    asm volatile("s_waitcnt lgkmcnt(0)");
    __builtin_amdgcn_s_barrier();
    __builtin_amdgcn_sched_barrier(0);
  };

  for (int i = 0; i < Tc; i += 4){
    ITER(i + 0, 0, 0, pfA);
    ITER(i + 1, 1, 1, pfB);
    ITER(i + 2, 0, 2, pfA);
    ITER(i + 3, 1, 3, pfB);
  }
  ITER(Tc, 0, 0, pfA);   // epilogue: layer1 of step Tc-1 + Hs slot Tc-1
  // save state (Tc even: finals in h0s[0], h1s[0])
  *(uint4*)(hst + (size_t)(b0 + row) * 128 + k0) = *(const uint4*)(&h0s[0][row * 136 + k0]);
  *(uint4*)(hst + 131072 + (size_t)(b0 + row) * 128 + k0) = *(const uint4*)(&h1s[0][row * 136 + k0]);
}

// ---------------- phase C1: dynn + x_mean/x_logvar ----------------
__global__ __launch_bounds__(512, 2) void k_c1(const u16* __restrict__ phi, const u16* __restrict__ Hs,
    const float* __restrict__ dw0, const float* __restrict__ db0,
    const float* __restrict__ dw1, const float* __restrict__ db1,
    const float* __restrict__ xmw, const float* __restrict__ xmb,
    const float* __restrict__ xlw, const float* __restrict__ xlb,
    u16* __restrict__ xmlv, int Tc){
  __shared__ __align__(16) u16 w0s[128 * 264];
  __shared__ __align__(16) u16 w1s[128 * 136];
  __shared__ __align__(16) u16 xws[32 * 136];
  __shared__ __align__(16) u16 buf[8][16 * 136];
  stage_weights(w0s, dw0, 128, 256, 256);
  stage_weights(w1s, dw1, 128, 128, 128);
  stage_weights(xws, xmw, 16, 128, 128);
  stage_weights(xws + 16 * 136, xlw, 16, 128, 128);
  int wv = threadIdx.x >> 6, l = threadIdx.x & 63;
  u16* mybuf = buf[wv];
  float b0v[8], b1v[8];
  #pragma unroll
  for (int nt = 0; nt < 8; nt++){
    b0v[nt] = db0[nt * 16 + (l & 15)];
    b1v[nt] = db1[nt * 16 + (l & 15)];
  }
  float bxm = xmb[l & 15], bxl = xlb[l & 15];
  __syncthreads();
  int tpb = Tc >> 4;
  int ntile = 1024 * tpb;
  int stride = gridDim.x * 8;
  for (int tile = blockIdx.x * 8 + wv; tile < ntile; tile += stride){
    int b = tile / tpb;
    int tt = (tile - b * tpb) << 4;
    size_t rbase = (size_t)(b * Tc + tt);
    const u16* ap = phi + rbase * 128;
    const u16* hp = Hs + rbase * 128;
    f32x4 acc[8];
    #pragma unroll
    for (int nt = 0; nt < 8; nt++) acc[nt] = zero4();
    #pragma unroll
    for (int ks = 0; ks < 8; ks++){
      short8 a = (ks < 4) ? gfrag(ap, 128, ks) : gfrag(hp, 128, ks - 4);
      #pragma unroll
      for (int nt = 0; nt < 8; nt++)
        acc[nt] = mfma16(a, frag_ld(w0s + nt * 16 * 264 + ks * 32, 264), acc[nt]);
    }
    #pragma unroll
    for (int nt = 0; nt < 8; nt++)
      acc_store_lds(mybuf, 136, nt * 16, acc[nt], b0v[nt], true);
    f32x4 a2[8];
    #pragma unroll
    for (int nt = 0; nt < 8; nt++) a2[nt] = zero4();
    #pragma unroll
    for (int ks = 0; ks < 4; ks++){
      short8 a = frag_ld(mybuf + ks * 32, 136);
      #pragma unroll
      for (int nt = 0; nt < 8; nt++)
        a2[nt] = mfma16(a, frag_ld(w1s + nt * 16 * 136 + ks * 32, 136), a2[nt]);
    }
    #pragma unroll
    for (int nt = 0; nt < 8; nt++)
      acc_store_lds(mybuf, 136, nt * 16, a2[nt], b1v[nt], false);
    f32x4 am = zero4(), al = zero4();
    #pragma unroll
    for (int ks = 0; ks < 4; ks++){
      short8 a = frag_ld(mybuf + ks * 32, 136);
      am = mfma16(a, frag_ld(xws + ks * 32, 136), am);
      al = mfma16(a, frag_ld(xws + 16 * 136 + ks * 32, 136), al);
    }
    acc_store_lds(mybuf, 136, 0, am, bxm, false);
    acc_store_lds(mybuf, 136, 16, al, bxl, false);
    u16* dst = xmlv + rbase * 32;
    int c = l;
    int row = c >> 2, k = (c & 3) * 8;
    *(short8*)(dst + row * 32 + k) = *(const short8*)(mybuf + row * 136 + k);
  }
}

// ---------------- phase C2: phi_x + menn + C@x_mean + loss ----------------
__global__ __launch_bounds__(512, 2) void k_c2(const u16* __restrict__ xmlv, const float* __restrict__ y,
    const float* __restrict__ pw0, const float* __restrict__ pb0,
    const float* __restrict__ pw1, const float* __restrict__ pb1,
    const float* __restrict__ mw0, const float* __restrict__ mb0,
    const float* __restrict__ mw1, const float* __restrict__ mb1,
    const float* __restrict__ Cw, float* __restrict__ out, int t0, int Tc){
  __shared__ __align__(16) u16 pw0s[128 * 40];
  __shared__ __align__(16) u16 pw1s[128 * 136];
  __shared__ __align__(16) u16 mw0s[128 * 136];
  __shared__ __align__(16) u16 mw1s[16 * 136];
  __shared__ __align__(16) u16 Cs[16 * 40];
  __shared__ __align__(16) u16 buf[8][16 * 136];
  stage_weights(pw0s, pw0, 128, 32, 32);
  stage_weights(pw1s, pw1, 128, 128, 128);
  stage_weights(mw0s, mw0, 128, 128, 128);
  stage_weights(mw1s, mw1, 16, 128, 128);
  stage_weights(Cs, Cw, 16, 16, 32);
  int wv = threadIdx.x >> 6, l = threadIdx.x & 63;
  u16* mybuf = buf[wv];
  float bp0v[8], bp1v[8], bm0v[8];
  #pragma unroll
  for (int nt = 0; nt < 8; nt++){
    bp0v[nt] = pb0[nt * 16 + (l & 15)];
    bp1v[nt] = pb1[nt * 16 + (l & 15)];
    bm0v[nt] = mb0[nt * 16 + (l & 15)];
  }
  float bm1 = mb1[l & 15];
  __syncthreads();
  float lacc = 0.f;
  int tpb = Tc >> 4;
  int ntile = 1024 * tpb;
  int stride = gridDim.x * 8;
  for (int tile = blockIdx.x * 8 + wv; tile < ntile; tile += stride){
    int b = tile / tpb;
    int tt = (tile - b * tpb) << 4;
    size_t rbase = (size_t)(b * Tc + tt);
    const u16* xp = xmlv + rbase * 32;
    short8 a0 = gfrag(xp, 32, 0);
    f32x4 acc[8];
    #pragma unroll
    for (int nt = 0; nt < 8; nt++)
      acc[nt] = mfma16(a0, frag_ld(pw0s + nt * 16 * 40, 40), zero4());
    #pragma unroll
    for (int nt = 0; nt < 8; nt++)
      acc_store_lds(mybuf, 136, nt * 16, acc[nt], bp0v[nt], true);
    f32x4 a2[8];
    #pragma unroll
    for (int nt = 0; nt < 8; nt++) a2[nt] = zero4();
    #pragma unroll
    for (int ks = 0; ks < 4; ks++){
      short8 a = frag_ld(mybuf + ks * 32, 136);
      #pragma unroll
      for (int nt = 0; nt < 8; nt++)
        a2[nt] = mfma16(a, frag_ld(pw1s + nt * 16 * 136 + ks * 32, 136), a2[nt]);
    }
    #pragma unroll
    for (int nt = 0; nt < 8; nt++)
      acc_store_lds(mybuf, 136, nt * 16, a2[nt], bp1v[nt], false);
    f32x4 a3[8];
    #pragma unroll
    for (int nt = 0; nt < 8; nt++) a3[nt] = zero4();
    #pragma unroll
    for (int ks = 0; ks < 4; ks++){
      short8 a = frag_ld(mybuf + ks * 32, 136);
      #pragma unroll
      for (int nt = 0; nt < 8; nt++)
        a3[nt] = mfma16(a, frag_ld(mw0s + nt * 16 * 136 + ks * 32, 136), a3[nt]);
    }
    #pragma unroll
    for (int nt = 0; nt < 8; nt++)
      acc_store_lds(mybuf, 136, nt * 16, a3[nt], bm0v[nt], true);
    f32x4 ay = zero4();
    #pragma unroll
    for (int ks = 0; ks < 4; ks++){
      short8 a = frag_ld(mybuf + ks * 32, 136);
      ay = mfma16(a, frag_ld(mw1s + ks * 32, 136), ay);
    }
    f32x4 ac = mfma16(a0, frag_ld(Cs, 40), zero4());
    #pragma unroll
    for (int r = 0; r < 4; r++){
      float yh = ay[r] + bm1 + ac[r];
      int m = (l >> 4) * 4 + r, j = l & 15;
      float d = yh - y[(size_t)(b * 16 + j) * 1024 + t0 + tt + m];
      lacc += d * d;
    }
  }
  #pragma unroll
  for (int off = 32; off > 0; off >>= 1)
    lacc += __shfl_down(lacc, off);
  if (l == 0) atomicAdd(out, lacc);
}

extern "C" void kernel_launch(void* const* d_in, const int* in_sizes, int n_in,
                              void* d_out, int out_size, void* d_ws, size_t ws_size,
                              hipStream_t stream){
  const float* u    = (const float*)d_in[0];
  const float* y    = (const float*)d_in[1];
  const float* h0   = (const float*)d_in[2];
  const float* puw0 = (const float*)d_in[3];
  const float* pub0 = (const float*)d_in[4];
  const float* puw1 = (const float*)d_in[5];
  const float* pub1 = (const float*)d_in[6];
  const float* dw0  = (const float*)d_in[7];
  const float* db0  = (const float*)d_in[8];
  const float* dw1  = (const float*)d_in[9];
  const float* db1  = (const float*)d_in[10];
  const float* xmw  = (const float*)d_in[11];
  const float* xmb  = (const float*)d_in[12];
  const float* xlw  = (const float*)d_in[13];
  const float* xlb  = (const float*)d_in[14];
  const float* pxw0 = (const float*)d_in[15];
  const float* pxb0 = (const float*)d_in[16];
  const float* pxw1 = (const float*)d_in[17];
  const float* pxb1 = (const float*)d_in[18];
  const float* mw0  = (const float*)d_in[19];
  const float* mb0  = (const float*)d_in[20];
  const float* mw1  = (const float*)d_in[21];
  const float* mb1  = (const float*)d_in[22];
  const float* gwih = (const float*)d_in[23];
  const float* gwhh = (const float*)d_in[24];
  const float* Cw   = (const float*)d_in[25];

  char* w = (char*)d_ws;
  u16* hst = (u16*)w; w += (size_t)2 * 1024 * 128 * 2;
  size_t head = (size_t)2 * 1024 * 128 * 2 + 4096;
  size_t avail = (ws_size > head) ? (ws_size - head) : 0;
  int Tc = 1024;
  while (Tc > 64 && (size_t)1024 * (size_t)Tc * (128 + 128 + 32) * 2 > avail) Tc >>= 1;
  u16* phi  = (u16*)w; w += (size_t)1024 * Tc * 128 * 2;
  u16* Hs   = (u16*)w; w += (size_t)1024 * Tc * 128 * 2;
  u16* xmlv = (u16*)w; w += (size_t)1024 * Tc * 32 * 2;

  hipMemsetAsync(d_out, 0, sizeof(float), stream);
  k_inith<<<1024, 256, 0, stream>>>(h0, hst);
  for (int t0 = 0; t0 < 1024; t0 += Tc){
    k_phiu<<<512, 512, 0, stream>>>(u, puw0, pub0, puw1, pub1, phi, t0, Tc);
    k_gru<<<64, 256, 0, stream>>>(phi, gwih, gwhh, hst, Hs, Tc);
    k_c1<<<256, 512, 0, stream>>>(phi, Hs, dw0, db0, dw1, db1, xmw, xmb, xlw, xlb, xmlv, Tc);
    k_c2<<<256, 512, 0, stream>>>(xmlv, y, pxw0, pxb0, pxw1, pxb1, mw0, mb0, mw1, mb1, Cw,
                                  (float*)d_out, t0, Tc);
  }
}

// Round 12
// 3259.124 us; speedup vs baseline: 1.1465x; 1.0454x over previous
//
#include <hip/hip_runtime.h>
#include <hip/hip_bf16.h>

typedef unsigned short u16;
typedef unsigned int u32;
using short8 = __attribute__((ext_vector_type(8))) short;
using f32x4  = __attribute__((ext_vector_type(4))) float;

#define DEVINL static __device__ __forceinline__

DEVINL float bf2f(u16 u){
  union { unsigned int i; float f; } x; x.i = ((unsigned int)u) << 16; return x.f;
}
DEVINL u16 f2bf(float f){
  union { float f; unsigned int i; } x; x.f = f;
  unsigned int i = x.i;
  return (u16)((i + 0x7FFFu + ((i >> 16) & 1u)) >> 16);
}
DEVINL u16 f2bf1(float f){
  __hip_bfloat16 b = __float2bfloat16(f);
  u16 u; __builtin_memcpy(&u, &b, 2); return u;
}
DEVINL float fast_sigm(float x){
  float e = __builtin_amdgcn_exp2f(x * -1.442695041f);
  return __builtin_amdgcn_rcpf(1.f + e);
}
DEVINL float fast_tanh(float x){
  x = fminf(fmaxf(x, -10.f), 10.f);
  float e = __builtin_amdgcn_exp2f(x * -2.885390082f);
  return (1.f - e) * __builtin_amdgcn_rcpf(1.f + e);
}
DEVINL f32x4 zero4(){ f32x4 z = {0.f, 0.f, 0.f, 0.f}; return z; }

DEVINL f32x4 mfma16(short8 a, short8 b, f32x4 c){
  return __builtin_amdgcn_mfma_f32_16x16x32_bf16(a, b, c, 0, 0, 0);
}

// lane l: row = l&15, k0 = (l>>4)*8 ; 16B vector read. stride in u16 elements
DEVINL short8 frag_ld(const u16* base, int stride){
  int l = threadIdx.x & 63;
  return *(const short8*)(base + (l & 15) * stride + ((l >> 4) << 3));
}
DEVINL short8 gfrag(const u16* rowbase, int stride, int ks){
  int l = threadIdx.x & 63;
  return *(const short8*)(rowbase + (size_t)(l & 15) * stride + ks * 32 + ((l >> 4) << 3));
}

DEVINL void acc_store_lds(u16* dst, int stride, int col_base, f32x4 acc, float bias, bool relu){
  int l = threadIdx.x & 63;
  int col = col_base + (l & 15);
  int row0 = (l >> 4) * 4;
  #pragma unroll
  for (int r = 0; r < 4; r++){
    float v = acc[r] + bias;
    if (relu) v = fmaxf(v, 0.f);
    dst[(row0 + r) * stride + col] = f2bf(v);
  }
}

DEVINL void stage_weights(u16* dst, const float* src, int N, int K, int Kp){
  int stride = Kp + 8;
  if (Kp > K){
    int padw = Kp - K;
    for (int i = threadIdx.x; i < N * padw; i += blockDim.x){
      int n = i / padw, k = K + (i - (i / padw) * padw);
      dst[n * stride + k] = 0;
    }
  }
  for (int i = threadIdx.x * 4; i < N * K; i += blockDim.x * 4){
    float4 v = *(const float4*)(src + i);
    int n = i / K, k = i - n * K;
    u16* d = dst + n * stride + k;
    d[0] = f2bf(v.x); d[1] = f2bf(v.y); d[2] = f2bf(v.z); d[3] = f2bf(v.w);
  }
}

__global__ __launch_bounds__(256) void k_inith(const float* __restrict__ h0, u16* __restrict__ hst){
  int i = blockIdx.x * 256 + threadIdx.x;
  if (i < 2 * 1024 * 128) hst[i] = f2bf(h0[i]);
}

// ================= role bodies (each carves the shared smem arena) =================

// ---- phi_u: 4 waves, per-wave tiles, blocks [64,192) ----
DEVINL void phiu_body(u16* smem, const float* u, const float* w0, const float* b0,
                      const float* w1, const float* b1, u16* phiW, int t0, int Tc){
  u16* w0s = smem;              // 128*40  = 5120
  u16* w1s = smem + 5120;       // 128*136 = 17408
  u16* buf = smem + 22528;      // 4 * 2176
  stage_weights(w0s, w0, 128, 16, 32);
  stage_weights(w1s, w1, 128, 128, 128);
  int wv = threadIdx.x >> 6, l = threadIdx.x & 63;
  u16* mybuf = buf + wv * 2176;
  float b0v[8], b1v[8];
  #pragma unroll
  for (int nt = 0; nt < 8; nt++){
    b0v[nt] = b0[nt * 16 + (l & 15)];
    b1v[nt] = b1[nt * 16 + (l & 15)];
  }
  __syncthreads();
  int tpb = Tc >> 4;
  int ntile = 1024 * tpb;
  int stride = 128 * 4;
  for (int tile = (blockIdx.x - 64) * 4 + wv; tile < ntile; tile += stride){
    int b = tile / tpb;
    int tt = (tile - b * tpb) << 4;
    int t = l & 15, kb = l >> 4;
    #pragma unroll
    for (int j = 0; j < 4; j++){
      int k = kb + j * 4;
      mybuf[t * 136 + k] = f2bf(u[(size_t)(b * 16 + k) * 1024 + t0 + tt + t]);
      mybuf[t * 136 + 16 + k] = 0;
    }
    short8 a0 = frag_ld(mybuf, 136);
    f32x4 acc[8];
    #pragma unroll
    for (int nt = 0; nt < 8; nt++)
      acc[nt] = mfma16(a0, frag_ld(w0s + nt * 16 * 40, 40), zero4());
    #pragma unroll
    for (int nt = 0; nt < 8; nt++)
      acc_store_lds(mybuf, 136, nt * 16, acc[nt], b0v[nt], true);
    f32x4 a2[8];
    #pragma unroll
    for (int nt = 0; nt < 8; nt++) a2[nt] = zero4();
    #pragma unroll
    for (int ks = 0; ks < 4; ks++){
      short8 a = frag_ld(mybuf + ks * 32, 136);
      #pragma unroll
      for (int nt = 0; nt < 8; nt++)
        a2[nt] = mfma16(a, frag_ld(w1s + nt * 16 * 136 + ks * 32, 136), a2[nt]);
    }
    #pragma unroll
    for (int nt = 0; nt < 8; nt++)
      acc_store_lds(mybuf, 136, nt * 16, a2[nt], b1v[nt], false);
    u16* dst = phiW + (size_t)(b * Tc + tt) * 128;
    #pragma unroll
    for (int j = 0; j < 4; j++){
      int c = j * 64 + l;
      int row = c >> 4, k = (c & 15) * 8;
      *(short8*)(dst + row * 128 + k) = *(const short8*)(mybuf + row * 136 + k);
    }
  }
}

// ---- GRU: r11 internals verbatim, blocks [0,64) ----
DEVINL void gru_body(u16* smem, const u16* __restrict__ phi,
                     const float* gwih, const float* gwhh,
                     u16* hst, u16* Hs, int Tc){
  u16* wi0 = smem;                    // 384*136 = 52224
  u16* h0sA[2] = { smem + 52224, smem + 54400 };
  u16* h1sA[2] = { smem + 56576, smem + 58752 };
  u16* pbA[4]  = { smem + 60928, smem + 63104, smem + 65280, smem + 67456 };
  const int l = threadIdx.x & 63;
  const int wv = threadIdx.x >> 6;          // 0..3
  const int b0 = blockIdx.x * 16;
  const int m0 = (l >> 4) * 4;
  const int cc = l & 15;
  const int nb = wv * 32;

  stage_weights(wi0, gwih, 384, 128, 128);  // layer0 W_ih in LDS

  const float* srcs[3] = { gwhh, gwih + 49152, gwhh + 49152 };
  short8 Wr[3][3][2][4];
  #pragma unroll
  for (int mm = 0; mm < 3; mm++){
    #pragma unroll
    for (int g = 0; g < 3; g++){
      #pragma unroll
      for (int nt = 0; nt < 2; nt++){
        int n = g * 128 + nb + nt * 16 + cc;
        #pragma unroll
        for (int ks = 0; ks < 4; ks++){
          const float* p = srcs[mm] + (size_t)n * 128 + ks * 32 + ((l >> 4) << 3);
          float4 va = *(const float4*)p;
          float4 vb = *(const float4*)(p + 4);
          short8 f;
          f[0] = (short)f2bf(va.x); f[1] = (short)f2bf(va.y);
          f[2] = (short)f2bf(va.z); f[3] = (short)f2bf(va.w);
          f[4] = (short)f2bf(vb.x); f[5] = (short)f2bf(vb.y);
          f[6] = (short)f2bf(vb.z); f[7] = (short)f2bf(vb.w);
          Wr[mm][g][nt][ks] = f;
        }
      }
    }
  }
  const int row = threadIdx.x >> 4, k0 = (threadIdx.x & 15) * 8;
  *(uint4*)(&h0sA[0][row * 136 + k0]) = *(const uint4*)(hst + (size_t)(b0 + row) * 128 + k0);
  *(uint4*)(&h1sA[0][row * 136 + k0]) = *(const uint4*)(hst + 131072 + (size_t)(b0 + row) * 128 + k0);
  float hp0[2][4], hp1[2][4];
  #pragma unroll
  for (int nt = 0; nt < 2; nt++)
    #pragma unroll
    for (int r = 0; r < 4; r++){
      hp0[nt][r] = bf2f(hst[(size_t)(b0 + m0 + r) * 128 + nb + nt * 16 + cc]);
      hp1[nt][r] = bf2f(hst[131072 + (size_t)(b0 + m0 + r) * 128 + nb + nt * 16 + cc]);
    }
  const u16* pL = phi + (size_t)(b0 + row) * Tc * 128 + k0;
  u16* Hp = Hs + (size_t)(b0 + row) * Tc * 128 + k0;
  *(uint4*)(&pbA[0][row * 136 + k0]) = *(const uint4*)(pL);
  *(uint4*)(&pbA[1][row * 136 + k0]) = *(const uint4*)(pL + 128);
  uint4 pfA = *(const uint4*)(pL + 2 * 128);
  uint4 pfB = *(const uint4*)(pL + 3 * 128);
  __syncthreads();

  auto ITER = [&](int i, int P, int q, uint4& pf){
    short8 a0[4];
    #pragma unroll
    for (int ks = 0; ks < 4; ks++) a0[ks] = frag_ld(h0sA[P] + ks * 32, 136);
    if (i > 0){
      short8 a1[4];
      #pragma unroll
      for (int ks = 0; ks < 4; ks++) a1[ks] = frag_ld(h1sA[P ^ 1] + ks * 32, 136);
      *(uint4*)(Hp + (size_t)(i - 1) * 128) = *(const uint4*)(&h1sA[P ^ 1][row * 136 + k0]);
      f32x4 cr[2], cz[2], cin[2], chn[2];
      #pragma unroll
      for (int nt = 0; nt < 2; nt++){ cr[nt]=zero4(); cz[nt]=zero4(); cin[nt]=zero4(); chn[nt]=zero4(); }
      #pragma unroll
      for (int ks = 0; ks < 4; ks++)
        #pragma unroll
        for (int nt = 0; nt < 2; nt++){
          cr[nt]  = mfma16(a0[ks], Wr[1][0][nt][ks], cr[nt]);
          cr[nt]  = mfma16(a1[ks], Wr[2][0][nt][ks], cr[nt]);
          cz[nt]  = mfma16(a0[ks], Wr[1][1][nt][ks], cz[nt]);
          cz[nt]  = mfma16(a1[ks], Wr[2][1][nt][ks], cz[nt]);
          cin[nt] = mfma16(a0[ks], Wr[1][2][nt][ks], cin[nt]);
          chn[nt] = mfma16(a1[ks], Wr[2][2][nt][ks], chn[nt]);
        }
      #pragma unroll
      for (int nt = 0; nt < 2; nt++)
        #pragma unroll
        for (int r = 0; r < 4; r++){
          float rg = fast_sigm(cr[nt][r]);
          float zg = fast_sigm(cz[nt][r]);
          float ng = fast_tanh(cin[nt][r] + rg * chn[nt][r]);
          float hv = zg * (hp1[nt][r] - ng) + ng;
          hp1[nt][r] = hv;
          h1sA[P][(m0 + r) * 136 + nb + nt * 16 + cc] = f2bf1(hv);
        }
    }
    if (i < Tc){
      short8 ap[4];
      #pragma unroll
      for (int ks = 0; ks < 4; ks++) ap[ks] = frag_ld(pbA[q] + ks * 32, 136);
      f32x4 cr[2], cz[2], cin[2], chn[2];
      #pragma unroll
      for (int nt = 0; nt < 2; nt++){ cr[nt]=zero4(); cz[nt]=zero4(); cin[nt]=zero4(); chn[nt]=zero4(); }
      #pragma unroll
      for (int ks = 0; ks < 4; ks++)
        #pragma unroll
        for (int nt = 0; nt < 2; nt++){
          cr[nt]  = mfma16(ap[ks], frag_ld(wi0 + (0 * 128 + nb + nt * 16) * 136 + ks * 32, 136), cr[nt]);
          cr[nt]  = mfma16(a0[ks], Wr[0][0][nt][ks], cr[nt]);
          cz[nt]  = mfma16(ap[ks], frag_ld(wi0 + (1 * 128 + nb + nt * 16) * 136 + ks * 32, 136), cz[nt]);
          cz[nt]  = mfma16(a0[ks], Wr[0][1][nt][ks], cz[nt]);
          cin[nt] = mfma16(ap[ks], frag_ld(wi0 + (2 * 128 + nb + nt * 16) * 136 + ks * 32, 136), cin[nt]);
          chn[nt] = mfma16(a0[ks], Wr[0][2][nt][ks], chn[nt]);
        }
      if (i + 2 < Tc) *(uint4*)(&pbA[(q + 2) & 3][row * 136 + k0]) = pf;
      if (i + 4 < Tc) pf = *(const uint4*)(pL + (size_t)(i + 4) * 128);
      #pragma unroll
      for (int nt = 0; nt < 2; nt++)
        #pragma unroll
        for (int r = 0; r < 4; r++){
          float rg = fast_sigm(cr[nt][r]);
          float zg = fast_sigm(cz[nt][r]);
          float ng = fast_tanh(cin[nt][r] + rg * chn[nt][r]);
          float hv = zg * (hp0[nt][r] - ng) + ng;
          hp0[nt][r] = hv;
          h0sA[P ^ 1][(m0 + r) * 136 + nb + nt * 16 + cc] = f2bf1(hv);
        }
    }
    __builtin_amdgcn_sched_barrier(0);
    asm volatile("s_waitcnt lgkmcnt(0)");
    __builtin_amdgcn_s_barrier();
    __builtin_amdgcn_sched_barrier(0);
  };

  for (int i = 0; i < Tc; i += 4){
    ITER(i + 0, 0, 0, pfA);
    ITER(i + 1, 1, 1, pfB);
    ITER(i + 2, 0, 2, pfA);
    ITER(i + 3, 1, 3, pfB);
  }
  ITER(Tc, 0, 0, pfA);
  *(uint4*)(hst + (size_t)(b0 + row) * 128 + k0) = *(const uint4*)(&h0sA[0][row * 136 + k0]);
  *(uint4*)(hst + 131072 + (size_t)(b0 + row) * 128 + k0) = *(const uint4*)(&h1sA[0][row * 136 + k0]);
}

// ---- c1: dynn + x_mean/x_logvar, blocks [192,320) ----
DEVINL void c1_body(u16* smem, const u16* phiC, const u16* HsC,
    const float* dw0, const float* db0, const float* dw1, const float* db1,
    const float* xmw, const float* xmb, const float* xlw, const float* xlb,
    u16* xmlv, int Tc){
  u16* w0s = smem;             // 128*264 = 33792
  u16* w1s = smem + 33792;     // 17408
  u16* xws = smem + 51200;     // 32*136 = 4352
  u16* buf = smem + 55552;     // 4*2176
  stage_weights(w0s, dw0, 128, 256, 256);
  stage_weights(w1s, dw1, 128, 128, 128);
  stage_weights(xws, xmw, 16, 128, 128);
  stage_weights(xws + 16 * 136, xlw, 16, 128, 128);
  int wv = threadIdx.x >> 6, l = threadIdx.x & 63;
  u16* mybuf = buf + wv * 2176;
  float b0v[8], b1v[8];
  #pragma unroll
  for (int nt = 0; nt < 8; nt++){
    b0v[nt] = db0[nt * 16 + (l & 15)];
    b1v[nt] = db1[nt * 16 + (l & 15)];
  }
  float bxm = xmb[l & 15], bxl = xlb[l & 15];
  __syncthreads();
  int tpb = Tc >> 4;
  int ntile = 1024 * tpb;
  int stride = 128 * 4;
  for (int tile = (blockIdx.x - 192) * 4 + wv; tile < ntile; tile += stride){
    int b = tile / tpb;
    int tt = (tile - b * tpb) << 4;
    size_t rbase = (size_t)(b * Tc + tt);
    const u16* ap = phiC + rbase * 128;
    const u16* hp = HsC + rbase * 128;
    f32x4 acc[8];
    #pragma unroll
    for (int nt = 0; nt < 8; nt++) acc[nt] = zero4();
    #pragma unroll
    for (int ks = 0; ks < 8; ks++){
      short8 a = (ks < 4) ? gfrag(ap, 128, ks) : gfrag(hp, 128, ks - 4);
      #pragma unroll
      for (int nt = 0; nt < 8; nt++)
        acc[nt] = mfma16(a, frag_ld(w0s + nt * 16 * 264 + ks * 32, 264), acc[nt]);
    }
    #pragma unroll
    for (int nt = 0; nt < 8; nt++)
      acc_store_lds(mybuf, 136, nt * 16, acc[nt], b0v[nt], true);
    f32x4 a2[8];
    #pragma unroll
    for (int nt = 0; nt < 8; nt++) a2[nt] = zero4();
    #pragma unroll
    for (int ks = 0; ks < 4; ks++){
      short8 a = frag_ld(mybuf + ks * 32, 136);
      #pragma unroll
      for (int nt = 0; nt < 8; nt++)
        a2[nt] = mfma16(a, frag_ld(w1s + nt * 16 * 136 + ks * 32, 136), a2[nt]);
    }
    #pragma unroll
    for (int nt = 0; nt < 8; nt++)
      acc_store_lds(mybuf, 136, nt * 16, a2[nt], b1v[nt], false);
    f32x4 am = zero4(), al = zero4();
    #pragma unroll
    for (int ks = 0; ks < 4; ks++){
      short8 a = frag_ld(mybuf + ks * 32, 136);
      am = mfma16(a, frag_ld(xws + ks * 32, 136), am);
      al = mfma16(a, frag_ld(xws + 16 * 136 + ks * 32, 136), al);
    }
    acc_store_lds(mybuf, 136, 0, am, bxm, false);
    acc_store_lds(mybuf, 136, 16, al, bxl, false);
    u16* dst = xmlv + rbase * 32;
    int c = l;
    int row = c >> 2, k = (c & 3) * 8;
    *(short8*)(dst + row * 32 + k) = *(const short8*)(mybuf + row * 136 + k);
  }
}

// ---- c2: phi_x + menn + C@x_mean + loss, blocks [320,448) ----
DEVINL void c2_body(u16* smem, const u16* xmlv, const float* y,
    const float* pw0, const float* pb0, const float* pw1, const float* pb1,
    const float* mw0, const float* mb0, const float* mw1, const float* mb1,
    const float* Cw, float* out, int t0, int Tc){
  u16* pw0s = smem;            // 5120
  u16* pw1s = smem + 5120;     // 17408
  u16* mw0s = smem + 22528;    // 17408
  u16* mw1s = smem + 39936;    // 2176
  u16* Cs   = smem + 42112;    // 640
  u16* buf  = smem + 42752;    // 4*2176
  stage_weights(pw0s, pw0, 128, 32, 32);
  stage_weights(pw1s, pw1, 128, 128, 128);
  stage_weights(mw0s, mw0, 128, 128, 128);
  stage_weights(mw1s, mw1, 16, 128, 128);
  stage_weights(Cs, Cw, 16, 16, 32);
  int wv = threadIdx.x >> 6, l = threadIdx.x & 63;
  u16* mybuf = buf + wv * 2176;
  float bp0v[8], bp1v[8], bm0v[8];
  #pragma unroll
  for (int nt = 0; nt < 8; nt++){
    bp0v[nt] = pb0[nt * 16 + (l & 15)];
    bp1v[nt] = pb1[nt * 16 + (l & 15)];
    bm0v[nt] = mb0[nt * 16 + (l & 15)];
  }
  float bm1 = mb1[l & 15];
  __syncthreads();
  float lacc = 0.f;
  int tpb = Tc >> 4;
  int ntile = 1024 * tpb;
  int stride = 128 * 4;
  for (int tile = (blockIdx.x - 320) * 4 + wv; tile < ntile; tile += stride){
    int b = tile / tpb;
    int tt = (tile - b * tpb) << 4;
    size_t rbase = (size_t)(b * Tc + tt);
    const u16* xp = xmlv + rbase * 32;
    short8 a0 = gfrag(xp, 32, 0);
    f32x4 acc[8];
    #pragma unroll
    for (int nt = 0; nt < 8; nt++)
      acc[nt] = mfma16(a0, frag_ld(pw0s + nt * 16 * 40, 40), zero4());
    #pragma unroll
    for (int nt = 0; nt < 8; nt++)
      acc_store_lds(mybuf, 136, nt * 16, acc[nt], bp0v[nt], true);
    f32x4 a2[8];
    #pragma unroll
    for (int nt = 0; nt < 8; nt++) a2[nt] = zero4();
    #pragma unroll
    for (int ks = 0; ks < 4; ks++){
      short8 a = frag_ld(mybuf + ks * 32, 136);
      #pragma unroll
      for (int nt = 0; nt < 8; nt++)
        a2[nt] = mfma16(a, frag_ld(pw1s + nt * 16 * 136 + ks * 32, 136), a2[nt]);
    }
    #pragma unroll
    for (int nt = 0; nt < 8; nt++)
      acc_store_lds(mybuf, 136, nt * 16, a2[nt], bp1v[nt], false);
    f32x4 a3[8];
    #pragma unroll
    for (int nt = 0; nt < 8; nt++) a3[nt] = zero4();
    #pragma unroll
    for (int ks = 0; ks < 4; ks++){
      short8 a = frag_ld(mybuf + ks * 32, 136);
      #pragma unroll
      for (int nt = 0; nt < 8; nt++)
        a3[nt] = mfma16(a, frag_ld(mw0s + nt * 16 * 136 + ks * 32, 136), a3[nt]);
    }
    #pragma unroll
    for (int nt = 0; nt < 8; nt++)
      acc_store_lds(mybuf, 136, nt * 16, a3[nt], bm0v[nt], true);
    f32x4 ay = zero4();
    #pragma unroll
    for (int ks = 0; ks < 4; ks++){
      short8 a = frag_ld(mybuf + ks * 32, 136);
      ay = mfma16(a, frag_ld(mw1s + ks * 32, 136), ay);
    }
    f32x4 ac = mfma16(a0, frag_ld(Cs, 40), zero4());
    #pragma unroll
    for (int r = 0; r < 4; r++){
      float yh = ay[r] + bm1 + ac[r];
      int m = (l >> 4) * 4 + r, j = l & 15;
      float d = yh - y[(size_t)(b * 16 + j) * 1024 + t0 + tt + m];
      lacc += d * d;
    }
  }
  #pragma unroll
  for (int off = 32; off > 0; off >>= 1)
    lacc += __shfl_down(lacc, off);
  if (l == 0) atomicAdd(out, lacc);
}

// ================= fused pipeline kernel =================
// launch j: phiu(j) | gru(j-1) | c1(j-2) | c2(j-3); roles gated by flags.
__global__ __launch_bounds__(256, 1) void k_fused(
    const float* __restrict__ u, const float* __restrict__ y,
    const float* puw0, const float* pub0, const float* puw1, const float* pub1,
    const float* dw0, const float* db0, const float* dw1, const float* db1,
    const float* xmw, const float* xmb, const float* xlw, const float* xlb,
    const float* pxw0, const float* pxb0, const float* pxw1, const float* pxb1,
    const float* mw0, const float* mb0, const float* mw1, const float* mb1,
    const float* Cw, const float* gwih, const float* gwhh,
    u16* phiW, const u16* phiG, const u16* phiC,
    u16* hst, u16* HsW, const u16* HsC,
    u16* xmW, const u16* xmC,
    float* out, int t0phiu, int t0c2, int Tc, int flags){
  __shared__ __align__(16) u16 smem[69632];   // 139264 B arena, unioned across roles
  if (blockIdx.x < 64){
    if (flags & 2) gru_body(smem, phiG, gwih, gwhh, hst, HsW, Tc);
  } else if (blockIdx.x < 192){
    if (flags & 1) phiu_body(smem, u, puw0, pub0, puw1, pub1, phiW, t0phiu, Tc);
  } else if (blockIdx.x < 320){
    if (flags & 4) c1_body(smem, phiC, HsC, dw0, db0, dw1, db1, xmw, xmb, xlw, xlb, xmW, Tc);
  } else {
    if (flags & 8) c2_body(smem, xmC, y, pxw0, pxb0, pxw1, pxb1, mw0, mb0, mw1, mb1, Cw, out, t0c2, Tc);
  }
}

extern "C" void kernel_launch(void* const* d_in, const int* in_sizes, int n_in,
                              void* d_out, int out_size, void* d_ws, size_t ws_size,
                              hipStream_t stream){
  const float* u    = (const float*)d_in[0];
  const float* y    = (const float*)d_in[1];
  const float* h0   = (const float*)d_in[2];
  const float* puw0 = (const float*)d_in[3];
  const float* pub0 = (const float*)d_in[4];
  const float* puw1 = (const float*)d_in[5];
  const float* pub1 = (const float*)d_in[6];
  const float* dw0  = (const float*)d_in[7];
  const float* db0  = (const float*)d_in[8];
  const float* dw1  = (const float*)d_in[9];
  const float* db1  = (const float*)d_in[10];
  const float* xmw  = (const float*)d_in[11];
  const float* xmb  = (const float*)d_in[12];
  const float* xlw  = (const float*)d_in[13];
  const float* xlb  = (const float*)d_in[14];
  const float* pxw0 = (const float*)d_in[15];
  const float* pxb0 = (const float*)d_in[16];
  const float* pxw1 = (const float*)d_in[17];
  const float* pxb1 = (const float*)d_in[18];
  const float* mw0  = (const float*)d_in[19];
  const float* mb0  = (const float*)d_in[20];
  const float* mw1  = (const float*)d_in[21];
  const float* mb1  = (const float*)d_in[22];
  const float* gwih = (const float*)d_in[23];
  const float* gwhh = (const float*)d_in[24];
  const float* Cw   = (const float*)d_in[25];

  const size_t hstE = (size_t)2 * 1024 * 128;
  // choose largest Tc with phi x3 + Hs x2 + xmlv x2 fitting
  int Tc = 128;
  while (Tc > 16){
    size_t needB = (hstE + (size_t)1024 * Tc * (3 * 128 + 2 * 128 + 2 * 32)) * 2 + 4096;
    if (needB <= ws_size) break;
    Tc >>= 1;
  }
  int NC = 1024 / Tc;
  size_t phiSz = (size_t)1024 * Tc * 128;   // elems; Hs slot same size
  size_t xmSz  = (size_t)1024 * Tc * 32;

  u16* hst  = (u16*)d_ws;
  u16* phiB = hst + hstE;
  u16* HsB  = phiB + 3 * phiSz;
  u16* xmB  = HsB + 2 * phiSz;

  hipMemsetAsync(d_out, 0, sizeof(float), stream);
  k_inith<<<1024, 256, 0, stream>>>(h0, hst);

  for (int j = 0; j <= NC + 2; j++){
    int flags = 0;
    if (j < NC) flags |= 1;                    // phiu(j)
    if (j >= 1 && j <= NC) flags |= 2;         // gru(j-1)
    if (j >= 2 && j <= NC + 1) flags |= 4;     // c1(j-2)
    if (j >= 3) flags |= 8;                    // c2(j-3)
    int s0 = j % 3, s1 = (j + 2) % 3, s2 = (j + 1) % 3;
    int hw = (j + 1) & 1, hc = j & 1;
    int xw = j & 1, xc = (j + 1) & 1;
    k_fused<<<448, 256, 0, stream>>>(
        u, y,
        puw0, pub0, puw1, pub1,
        dw0, db0, dw1, db1, xmw, xmb, xlw, xlb,
        pxw0, pxb0, pxw1, pxb1, mw0, mb0, mw1, mb1,
        Cw, gwih, gwhh,
        phiB + (size_t)s0 * phiSz, phiB + (size_t)s1 * phiSz, phiB + (size_t)s2 * phiSz,
        hst, HsB + (size_t)hw * phiSz, HsB + (size_t)hc * phiSz,
        xmB + (size_t)xw * xmSz, xmB + (size_t)xc * xmSz,
        (float*)d_out, j * Tc, (j - 3) * Tc, Tc, flags);
  }
}